// Round 2
// baseline (606.684 us; speedup 1.0000x reference)
//
#include <hip/hip_runtime.h>

// ConvCapsuleLayer: 5x5 SAME conv (128 folded images, 16->256 ch) + 3x dynamic routing.
// Block = 4 consecutive w-positions of one (b,h) row; thread = output channel.
// W slice (16 floats) reused across 4 positions x 8 input caps = 512 FMA / 16 loads.

#define HH    32
#define WWID  32
#define INC   8
#define INA   16
#define KS    5
#define OUTC  8
#define OUTA  32
#define CHN   256   // OUTC*OUTA
#define PPOS  4     // output positions per block (along w)

__global__ __launch_bounds__(256) void capsconv_route_kernel(
    const float* __restrict__ inp,   // [16][32][32][8][16]
    const float* __restrict__ Wt,    // [5][5][16][256]
    const float* __restrict__ bias,  // [256]
    float* __restrict__ out)         // [16][32][32][8][32]
{
  const int tid = threadIdx.x;          // ch = c*32 + a
  const int bid = blockIdx.x;
  const int w0 = (bid & 7) * PPOS;
  const int h0 = (bid >> 3) & 31;
  const int bb = bid >> 8;              // output batch
  // TF reshape scramble: votes[bb][ii] = conv image n = bb*8+ii,
  // image n reads inputs[b_src = n%16][...][i_src = n/16][...]
  const int i_src = bb >> 1;
  const int b_base = (bb & 1) * 8;      // b_src = b_base + ii

  // ---- conv: acc[position][input capsule] ----
  float acc[PPOS][8];
  #pragma unroll
  for (int p = 0; p < PPOS; ++p)
    #pragma unroll
    for (int i = 0; i < 8; ++i) acc[p][i] = 0.f;

  #pragma unroll 1
  for (int kh = 0; kh < KS; ++kh) {
    const int hh = h0 + kh - 2;
    if ((unsigned)hh >= HH) continue;
    #pragma unroll 1
    for (int kw = 0; kw < KS; ++kw) {
      // W slice for this (kh,kw): 16 coalesced loads, held in VGPRs
      const float* wp = Wt + (size_t)((kh * KS + kw) * INA) * CHN + tid;
      float wreg[INA];
      #pragma unroll
      for (int ia = 0; ia < INA; ++ia) wreg[ia] = wp[(size_t)ia * CHN];
      #pragma unroll
      for (int p = 0; p < PPOS; ++p) {
        const int ww = w0 + p + kw - 2;
        if ((unsigned)ww >= WWID) continue;
        #pragma unroll
        for (int i = 0; i < 8; ++i) {
          // block-uniform address -> scalar loads (SGPR broadcast into v_fmac)
          const float* xp = inp + ((((size_t)(b_base + i) * HH + hh) * WWID + ww) * INC + i_src) * INA;
          #pragma unroll
          for (int ia = 0; ia < INA; ++ia)
            acc[p][i] = fmaf(xp[ia], wreg[ia], acc[p][i]);
        }
      }
    }
  }

  // ---- dynamic routing (3 iterations) ----
  const int c = tid >> 5;               // output capsule
  const float bv = bias[tid];
  float logit[PPOS][8];
  float act[PPOS];
  __shared__ float lds_logit[PPOS][8][8];   // [p][ii][c]

  // r = 0: softmax(zeros) = 1/8 uniform
  #pragma unroll
  for (int p = 0; p < PPOS; ++p) {
    float s = 0.f;
    #pragma unroll
    for (int i = 0; i < 8; ++i) s += acc[p][i];
    float preact = fmaf(0.125f, s, bv);
    float nsq = preact * preact;
    #pragma unroll
    for (int m = 16; m >= 1; m >>= 1) nsq += __shfl_xor(nsq, m, 64);
    float norm = sqrtf(nsq);
    act[p] = preact * (norm / (1.f + nsq));
    #pragma unroll
    for (int i = 0; i < 8; ++i) {
      float d = acc[p][i] * act[p];
      #pragma unroll
      for (int m = 16; m >= 1; m >>= 1) d += __shfl_xor(d, m, 64);
      logit[p][i] = d;
    }
  }

  for (int r = 1; r < 3; ++r) {
    if ((tid & 31) == 0) {
      #pragma unroll
      for (int p = 0; p < PPOS; ++p)
        #pragma unroll
        for (int i = 0; i < 8; ++i) lds_logit[p][i][c] = logit[p][i];
    }
    __syncthreads();
    #pragma unroll
    for (int p = 0; p < PPOS; ++p) {
      float preact = bv;
      #pragma unroll
      for (int i = 0; i < 8; ++i) {
        float l[8];
        #pragma unroll
        for (int cc = 0; cc < 8; ++cc) l[cc] = lds_logit[p][i][cc];
        float mx = fmaxf(fmaxf(fmaxf(l[0], l[1]), fmaxf(l[2], l[3])),
                         fmaxf(fmaxf(l[4], l[5]), fmaxf(l[6], l[7])));
        float den = 0.f;
        #pragma unroll
        for (int cc = 0; cc < 8; ++cc) den += __expf(l[cc] - mx);
        float route = __expf(logit[p][i] - mx) / den;
        preact = fmaf(route, acc[p][i], preact);
      }
      float nsq = preact * preact;
      #pragma unroll
      for (int m = 16; m >= 1; m >>= 1) nsq += __shfl_xor(nsq, m, 64);
      float norm = sqrtf(nsq);
      act[p] = preact * (norm / (1.f + nsq));
      if (r < 2) {
        #pragma unroll
        for (int i = 0; i < 8; ++i) {
          float d = acc[p][i] * act[p];
          #pragma unroll
          for (int m = 16; m >= 1; m >>= 1) d += __shfl_xor(d, m, 64);
          logit[p][i] += d;
        }
      }
    }
    __syncthreads();
  }

  // out[bb][h0][w0+p][c][a] : (bid*PPOS+p)*256 + tid (coalesced)
  #pragma unroll
  for (int p = 0; p < PPOS; ++p)
    out[((size_t)bid * PPOS + p) * CHN + tid] = act[p];
}

extern "C" void kernel_launch(void* const* d_in, const int* in_sizes, int n_in,
                              void* d_out, int out_size, void* d_ws, size_t ws_size,
                              hipStream_t stream) {
  (void)in_sizes; (void)n_in; (void)d_ws; (void)ws_size; (void)out_size;
  const float* inp  = (const float*)d_in[0];
  const float* Wt   = (const float*)d_in[1];
  const float* bv   = (const float*)d_in[2];
  float* out        = (float*)d_out;
  dim3 grid(16 * 32 * 8);    // (b, h, w/4)
  dim3 block(256);
  hipLaunchKernelGGL(capsconv_route_kernel, grid, block, 0, stream, inp, Wt, bv, out);
}

// Round 4
// 174.392 us; speedup vs baseline: 3.4788x; 3.4788x over previous
//
#include <hip/hip_runtime.h>

// ConvCapsuleLayer via fp16 MFMA GEMM + fused dynamic routing.
// Main kernel: block = one (bb,h) row. GEMM M=256 rows (r = w*8 + ii),
// N=256 channels, K=400 = 5 kh x 5 kw x 16 ia (one 32x32x16 MFMA per tap).
// Routing done in 4 chunks of 8 w-positions from LDS votes.
// fp16 (not bf16): rel rounding 2^-11 vs 2^-9 -> vote absmax ~6e-3 < 1.5e-2 thr.

typedef __attribute__((ext_vector_type(8))) _Float16 f16x8;
typedef __attribute__((ext_vector_type(16))) float f32x16;

__device__ __forceinline__ unsigned short f2h(float x) {
  union { _Float16 h; unsigned short u; } v;
  v.h = (_Float16)x;                 // v_cvt_f16_f32, round-to-nearest-even
  return v.u;
}

// W[5][5][16][256] f32  ->  wsh fp16 [khkw 25][ch 256][ia 16]
__global__ __launch_bounds__(256) void wprep_kernel(
    const float* __restrict__ W, unsigned short* __restrict__ wsh) {
  int t = blockIdx.x * 256 + threadIdx.x;      // 102400 total
  int khkw = t >> 12;
  int rem  = t & 4095;
  int ch = rem >> 4, ia = rem & 15;
  wsh[t] = f2h(W[khkw * 4096 + ia * 256 + ch]);
}

#define XROW 1168   // bytes per ii row in X LDS: 36 w * 32B + 16B pad (bank balance)

__global__ __launch_bounds__(512, 2) void capsconv_mfma_kernel(
    const float* __restrict__ inp,            // [16][32][32][8][16] f32
    const unsigned short* __restrict__ wsh,   // [25][256][16] fp16
    const float* __restrict__ bias,           // [256] f32
    float* __restrict__ out)                  // [16][32][32][256] f32
{
  __shared__ char smem[77824];
  // staging phase: X fp16 at [0, 9344), W fp16 at [9344, 50304)
  // routing phase: votes f32[8w][8ii][256ch] at 0..65536, act f32[8][256] at 65536,
  //                logits f32[8*8*8] at 73728, route f32[8*8*8] at 75776
  unsigned short* Xl = (unsigned short*)smem;
  unsigned short* Wl = (unsigned short*)(smem + 9344);
  float* votes = (float*)smem;
  float* actl  = (float*)(smem + 65536);
  float* logit = (float*)(smem + 73728);
  float* route = (float*)(smem + 75776);

  const int tid  = threadIdx.x;
  const int wid  = tid >> 6;
  const int lane = tid & 63;
  const int sub  = lane >> 5;
  const int wave_m = wid >> 1;   // 0..3 -> rows [wave_m*64, +64) -> w chunk wave_m
  const int wave_n = wid & 1;    // 0..1 -> ch [wave_n*128, +128)

  const int bid = blockIdx.x;    // 512 = bb*32 + h
  const int h  = bid & 31;
  const int bb = bid >> 5;
  const int i_src  = bb >> 1;          // TF reshape scramble (verified r1)
  const int b_base = (bb & 1) * 8;

  f32x16 acc[2][4];
  #pragma unroll
  for (int mt = 0; mt < 2; ++mt)
    #pragma unroll
    for (int nt = 0; nt < 4; ++nt)
      #pragma unroll
      for (int e = 0; e < 16; ++e) acc[mt][nt][e] = 0.f;

  // ---------------- conv GEMM over 5 kh ----------------
  for (int kh = 0; kh < 5; ++kh) {
    const int hh = h + kh - 2;
    const bool hok = ((unsigned)hh < 32u);
    __syncthreads();
    if (hok) {
      // X slice: [8 ii][36 wpad][16 ia] fp16, zero-padded at wpad<2, wpad>=34
      for (int e = tid; e < 4608; e += 512) {
        int ii = e / 576; int rem = e - ii * 576;
        int wpad = rem >> 4; int ia = rem & 15;
        int wsrc = wpad - 2;
        float v = 0.f;
        if ((unsigned)wsrc < 32u)
          v = inp[((((size_t)(b_base + ii) * 32 + hh) * 32 + wsrc) * 8 + i_src) * 16 + ia];
        Xl[ii * (XROW / 2) + wpad * 16 + ia] = f2h(v);
      }
      // W slice for this kh: [5 kw][256 ch][16 ia] fp16 = 20480 elems (linear copy)
      const unsigned short* wp = wsh + (size_t)kh * 20480;
      for (int c = tid; c < 2560; c += 512)
        *(f16x8*)(Wl + c * 8) = *(const f16x8*)(wp + c * 8);
    }
    __syncthreads();
    if (!hok) continue;

    #pragma unroll
    for (int kw = 0; kw < 5; ++kw) {
      f16x8 afrag[2], bfrag[4];
      #pragma unroll
      for (int mt = 0; mt < 2; ++mt) {
        int r = wave_m * 64 + mt * 32 + (lane & 31);   // r = w*8 + ii
        int w = r >> 3, ii = r & 7;
        afrag[mt] = *(const f16x8*)(smem + ii * XROW + (w + kw) * 32 + sub * 16);
      }
      #pragma unroll
      for (int nt = 0; nt < 4; ++nt) {
        int ch = wave_n * 128 + nt * 32 + (lane & 31);
        bfrag[nt] = *(const f16x8*)(smem + 9344 + kw * 8192 + ch * 32 + sub * 16);
      }
      #pragma unroll
      for (int mt = 0; mt < 2; ++mt)
        #pragma unroll
        for (int nt = 0; nt < 4; ++nt)
          acc[mt][nt] = __builtin_amdgcn_mfma_f32_32x32x16_f16(
              afrag[mt], bfrag[nt], acc[mt][nt], 0, 0, 0);
    }
  }

  // ---------------- routing (4 chunks of 8 w) ----------------
  const int chv  = tid & 255;        // channel owned in weighted-sum phase
  const int cv   = chv >> 5;
  const float bv = bias[chv];
  const int wsel = tid >> 8;         // 0/1
  const int ag_w  = tid >> 6;        // agreement task: (w, ii, c)
  const int ag_ii = (tid >> 3) & 7;
  const int ag_c  = tid & 7;
  const int rot   = tid & 31;

  for (int chunk = 0; chunk < 4; ++chunk) {
    __syncthreads();
    if (wave_m == chunk) {   // these 2 waves own rows r in [chunk*64, +64)
      #pragma unroll
      for (int mt = 0; mt < 2; ++mt)
        #pragma unroll
        for (int nt = 0; nt < 4; ++nt)
          #pragma unroll
          for (int reg = 0; reg < 16; ++reg) {
            int rl = (reg & 3) + ((reg >> 2) << 3) + (sub << 2);  // C/D row (m74/m101)
            int r  = mt * 32 + rl;          // 0..63 within chunk
            int wloc = r >> 3;              // 0..7
            int ii   = r & 7;
            int ch   = wave_n * 128 + nt * 32 + (lane & 31);
            votes[(wloc * 8 + ii) * 256 + ch] = acc[mt][nt][reg];
          }
    }
    __syncthreads();

    for (int rt = 0; rt < 3; ++rt) {
      if (rt > 0) {
        // softmax over output caps for each (w, ii)
        int base = tid & ~7;
        float mx = logit[base];
        #pragma unroll
        for (int j = 1; j < 8; ++j) mx = fmaxf(mx, logit[base + j]);
        float den = 0.f;
        #pragma unroll
        for (int j = 0; j < 8; ++j) den += __expf(logit[base + j] - mx);
        route[tid] = __expf(logit[tid] - mx) / den;
        __syncthreads();
      }
      // weighted sum over ii + squash; write act (or final output)
      for (int p = 0; p < 4; ++p) {
        int wl = p * 2 + wsel;
        const float* vp = votes + wl * 2048 + chv;
        float pre = bv;
        if (rt == 0) {
          float s = 0.f;
          #pragma unroll
          for (int ii = 0; ii < 8; ++ii) s += vp[ii * 256];
          pre = fmaf(0.125f, s, pre);
        } else {
          const float* rp = route + wl * 64 + cv;
          #pragma unroll
          for (int ii = 0; ii < 8; ++ii) pre = fmaf(rp[ii * 8], vp[ii * 256], pre);
        }
        float nsq = pre * pre;
        #pragma unroll
        for (int m = 16; m >= 1; m >>= 1) nsq += __shfl_xor(nsq, m, 64);
        float av = pre * (sqrtf(nsq) / (1.f + nsq));
        if (rt == 2)
          out[((size_t)(bb * 32 + h) * 32 + chunk * 8 + wl) * 256 + chv] = av;
        else
          actl[wl * 256 + chv] = av;
      }
      __syncthreads();
      if (rt < 2) {
        // agreement: dot(votes, act) over 32 atoms; one (w,ii,c) per thread
        const float* vp = votes + (ag_w * 8 + ag_ii) * 256 + ag_c * 32;
        const float* ap = actl + ag_w * 256 + ag_c * 32;
        float dot = 0.f;
        #pragma unroll
        for (int s = 0; s < 32; ++s) {
          int a = (s + rot) & 31;       // bank-rotated
          dot = fmaf(vp[a], ap[a], dot);
        }
        if (rt == 0) logit[tid] = dot; else logit[tid] += dot;
        __syncthreads();
      }
    }
  }
}

extern "C" void kernel_launch(void* const* d_in, const int* in_sizes, int n_in,
                              void* d_out, int out_size, void* d_ws, size_t ws_size,
                              hipStream_t stream) {
  (void)in_sizes; (void)n_in; (void)ws_size; (void)out_size;
  const float* inp  = (const float*)d_in[0];
  const float* W    = (const float*)d_in[1];
  const float* bv   = (const float*)d_in[2];
  float* out        = (float*)d_out;
  unsigned short* wsh = (unsigned short*)d_ws;   // 204800 B used

  hipLaunchKernelGGL(wprep_kernel, dim3(400), dim3(256), 0, stream, W, wsh);
  hipLaunchKernelGGL(capsconv_mfma_kernel, dim3(512), dim3(512), 0, stream,
                     inp, wsh, bv, out);
}

// Round 5
// 72.519 us; speedup vs baseline: 8.3659x; 2.4048x over previous
//
#include <hip/hip_runtime.h>

// ConvCapsuleLayer: fp16 MFMA conv GEMM + fused routing, spill-free.
// Block = 256 thr (4 waves), tile M=64 rows (8 w-pos, r = w*8+ii), N=256 ch.
// Wave = 64x64 tile -> acc[2][2] f32x16 = 64 VGPR. W read direct from L2.
// Votes kept in LDS as fp16 [w][ch][ii]; routing data-parallel.

typedef __attribute__((ext_vector_type(8))) _Float16 f16x8;
typedef __attribute__((ext_vector_type(16))) float f32x16;

__device__ __forceinline__ unsigned short f2h(float x) {
  union { _Float16 h; unsigned short u; } v;
  v.h = (_Float16)x;
  return v.u;
}

// W[5][5][16][256] f32 -> wsh fp16 [khkw 25][ch 256][ia 16]
__global__ __launch_bounds__(256) void wprep_kernel(
    const float* __restrict__ W, unsigned short* __restrict__ wsh) {
  int t = blockIdx.x * 256 + threadIdx.x;      // 102400 total
  int khkw = t >> 12;
  int rem  = t & 4095;
  int ch = rem >> 4, ia = rem & 15;
  wsh[t] = f2h(W[khkw * 4096 + ia * 256 + ch]);
}

// LDS map (bytes):
//   staging (conv phase, aliased): X fp16 [8 ii][stride 200 el][12 wl][16 ia] = 3200 B @0
//   routing: votesH fp16 [8 w][256 ch][8 ii] = 32768 @0
//            actL  f32 [8 w][256]            =  8192 @32768
//            logitL f32 [8 w][8 ii][8 c]     =  2048 @40960
//            routeH fp16 [8 w][8 c][8 ii]    =  1024 @43008
__global__ __launch_bounds__(256, 3) void capsconv_mfma_kernel(
    const float* __restrict__ inp,            // [16][32][32][8][16] f32
    const unsigned short* __restrict__ wsh,   // [25][256][16] fp16
    const float* __restrict__ bias,           // [256] f32
    float* __restrict__ out)                  // [16][32][32][256] f32
{
  __shared__ char smem[44032];
  const _Float16* wshh = (const _Float16*)wsh;
  _Float16* votesH = (_Float16*)smem;
  float* actL   = (float*)(smem + 32768);
  float* logitL = (float*)(smem + 40960);
  _Float16* routeH = (_Float16*)(smem + 43008);

  const int tid  = threadIdx.x;
  const int wid  = tid >> 6;          // wave 0..3 -> ch quarter
  const int lane = tid & 63;
  const int sub  = lane >> 5;
  const int ln31 = lane & 31;

  const int bid = blockIdx.x;         // 2048 = ((bb*32 + h)*4 + wq)
  const int wq = bid & 3;
  const int h  = (bid >> 2) & 31;
  const int bb = bid >> 7;
  const int i_src  = bb >> 1;         // TF reshape scramble (verified r1/r4)
  const int b_base = (bb & 1) * 8;

  f32x16 acc[2][2];
  #pragma unroll
  for (int mt = 0; mt < 2; ++mt)
    #pragma unroll
    for (int nt = 0; nt < 2; ++nt)
      #pragma unroll
      for (int e = 0; e < 16; ++e) acc[mt][nt][e] = 0.f;

  // ---------------- conv over 5 kh ----------------
  for (int kh = 0; kh < 5; ++kh) {
    const int hh = h + kh - 2;
    const bool hok = ((unsigned)hh < 32u);
    __syncthreads();
    if (hok) {
      // X: [8 ii][12 wl][16 ia] fp16, ii-stride 200 el (bank +4), halo w +-2
      for (int e = tid; e < 384; e += 256) {
        int ii = e / 48; int rem = e - ii * 48;
        int wl = rem >> 2; int iaq = rem & 3;
        int wsrc = wq * 8 + wl - 2;
        float4 v = make_float4(0.f, 0.f, 0.f, 0.f);
        if ((unsigned)wsrc < 32u)
          v = *(const float4*)(inp +
              ((((size_t)(b_base + ii) * 32 + hh) * 32 + wsrc) * 8 + i_src) * 16 + iaq * 4);
        union { _Float16 hx[4]; unsigned long long u; } pk;
        pk.hx[0] = (_Float16)v.x; pk.hx[1] = (_Float16)v.y;
        pk.hx[2] = (_Float16)v.z; pk.hx[3] = (_Float16)v.w;
        *(unsigned long long*)(smem + ii * 400 + wl * 32 + iaq * 8) = pk.u;
      }
    }
    __syncthreads();
    if (!hok) continue;

    #pragma unroll
    for (int kw = 0; kw < 5; ++kw) {
      f16x8 afrag[2], bfrag[2];
      #pragma unroll
      for (int mt = 0; mt < 2; ++mt) {
        int r = mt * 32 + ln31;                 // block row: w_local = r>>3, ii = r&7
        afrag[mt] = *(const f16x8*)(smem + (r & 7) * 400 + ((r >> 3) + kw) * 32 + sub * 16);
      }
      #pragma unroll
      for (int nt = 0; nt < 2; ++nt) {
        int ch = wid * 64 + nt * 32 + ln31;
        bfrag[nt] = *(const f16x8*)(wshh + (size_t)(kh * 5 + kw) * 4096 + ch * 16 + sub * 8);
      }
      #pragma unroll
      for (int mt = 0; mt < 2; ++mt)
        #pragma unroll
        for (int nt = 0; nt < 2; ++nt)
          acc[mt][nt] = __builtin_amdgcn_mfma_f32_32x32x16_f16(
              afrag[mt], bfrag[nt], acc[mt][nt], 0, 0, 0);
    }
  }

  // ---------------- votes -> LDS fp16 [w][ch][ii] ----------------
  __syncthreads();
  #pragma unroll
  for (int mt = 0; mt < 2; ++mt)
    #pragma unroll
    for (int nt = 0; nt < 2; ++nt) {
      int ch = wid * 64 + nt * 32 + ln31;
      #pragma unroll
      for (int q = 0; q < 4; ++q) {
        // regs 4q..4q+3: row = (t) + 8q + 4sub -> w = mt*4+q, ii = t + 4sub
        int w = mt * 4 + q;
        union { _Float16 hx[4]; unsigned long long u; } pk;
        #pragma unroll
        for (int t = 0; t < 4; ++t) pk.hx[t] = (_Float16)acc[mt][nt][q * 4 + t];
        *(unsigned long long*)((char*)votesH + ((w * 256 + ch) * 8 + sub * 4) * 2) = pk.u;
      }
    }
  __syncthreads();

  // ---------------- routing ----------------
  const int c_own = tid >> 5;
  const float bv = bias[tid];
  const int ag_w = tid >> 5;          // agreement task: (w, c, g)
  const int ag_c = (tid >> 2) & 7;
  const int ag_g = tid & 3;

  for (int rt = 0; rt < 3; ++rt) {
    if (rt > 0) {
      if (tid < 64) {                 // softmax over c per (w, ii)
        int wv = tid >> 3, ii = tid & 7;
        float l[8];
        #pragma unroll
        for (int c = 0; c < 8; ++c) l[c] = logitL[(wv * 8 + ii) * 8 + c];
        float mx = fmaxf(fmaxf(fmaxf(l[0], l[1]), fmaxf(l[2], l[3])),
                         fmaxf(fmaxf(l[4], l[5]), fmaxf(l[6], l[7])));
        float den = 0.f;
        #pragma unroll
        for (int c = 0; c < 8; ++c) den += __expf(l[c] - mx);
        float inv = 1.f / den;
        #pragma unroll
        for (int c = 0; c < 8; ++c)
          routeH[(wv * 8 + c) * 8 + ii] = (_Float16)(__expf(l[c] - mx) * inv);
      }
      __syncthreads();
    }
    // weighted sum + squash; thread owns ch = tid
    #pragma unroll 1
    for (int w = 0; w < 8; ++w) {
      f16x8 vp = *(const f16x8*)(votesH + (w * 256 + tid) * 8);
      float pre = bv;
      if (rt == 0) {
        float s = 0.f;
        #pragma unroll
        for (int i = 0; i < 8; ++i) s += (float)vp[i];
        pre = fmaf(0.125f, s, pre);
      } else {
        f16x8 rp = *(const f16x8*)(routeH + (w * 8 + c_own) * 8);
        #pragma unroll
        for (int i = 0; i < 8; ++i) pre = fmaf((float)rp[i], (float)vp[i], pre);
      }
      float nsq = pre * pre;
      #pragma unroll
      for (int m = 16; m >= 1; m >>= 1) nsq += __shfl_xor(nsq, m, 64);
      float av = pre * (sqrtf(nsq) / (1.f + nsq));
      if (rt == 2)
        out[((size_t)((bb * 32 + h) * 32 + wq * 8 + w)) * 256 + tid] = av;
      else
        actL[w * 256 + tid] = av;
    }
    if (rt < 2) {
      __syncthreads();
      // agreement: dot(vote, act) over 32 atoms; (w,c) split over 4 g-lanes
      float dot8[8];
      #pragma unroll
      for (int i = 0; i < 8; ++i) dot8[i] = 0.f;
      #pragma unroll
      for (int j0 = 0; j0 < 8; ++j0) {
        int a = ag_g * 8 + ((j0 + ag_c) & 7);       // c-staggered banks
        f16x8 vp = *(const f16x8*)(votesH + (ag_w * 256 + ag_c * 32 + a) * 8);
        float av = actL[ag_w * 256 + ag_c * 32 + a];
        #pragma unroll
        for (int ii = 0; ii < 8; ++ii) dot8[ii] = fmaf((float)vp[ii], av, dot8[ii]);
      }
      #pragma unroll
      for (int ii = 0; ii < 8; ++ii) {
        dot8[ii] += __shfl_xor(dot8[ii], 1, 64);
        dot8[ii] += __shfl_xor(dot8[ii], 2, 64);
      }
      if (ag_g == 0) {
        #pragma unroll
        for (int ii = 0; ii < 8; ++ii) {
          int idx = (ag_w * 8 + ii) * 8 + ag_c;
          if (rt == 0) logitL[idx] = dot8[ii];
          else         logitL[idx] += dot8[ii];
        }
      }
      __syncthreads();
    }
  }
}

extern "C" void kernel_launch(void* const* d_in, const int* in_sizes, int n_in,
                              void* d_out, int out_size, void* d_ws, size_t ws_size,
                              hipStream_t stream) {
  (void)in_sizes; (void)n_in; (void)ws_size; (void)out_size;
  const float* inp  = (const float*)d_in[0];
  const float* W    = (const float*)d_in[1];
  const float* bv   = (const float*)d_in[2];
  float* out        = (float*)d_out;
  unsigned short* wsh = (unsigned short*)d_ws;   // 204800 B used

  hipLaunchKernelGGL(wprep_kernel, dim3(400), dim3(256), 0, stream, W, wsh);
  hipLaunchKernelGGL(capsconv_mfma_kernel, dim3(2048), dim3(256), 0, stream,
                     inp, wsh, bv, out);
}

// Round 6
// 71.304 us; speedup vs baseline: 8.5084x; 1.0170x over previous
//
#include <hip/hip_runtime.h>

// ConvCapsuleLayer: fp16 MFMA conv GEMM + fused routing.
// Block = 256 thr (4 waves), tile M=64 rows (8 w-pos, r = w*8+ii), N=256 ch.
// r6: all-5-rows X staging (barrier-free conv), XOR-swizzled votes LDS,
//     fp16 act, reg-cached wsum votes, 4 blocks/CU.

typedef __attribute__((ext_vector_type(8))) _Float16 f16x8;
typedef __attribute__((ext_vector_type(16))) float f32x16;

__device__ __forceinline__ unsigned short f2h(float x) {
  union { _Float16 h; unsigned short u; } v;
  v.h = (_Float16)x;
  return v.u;
}

// W[5][5][16][256] f32 -> wsh fp16 [khkw 25][ch 256][ia 16]
__global__ __launch_bounds__(256) void wprep_kernel(
    const float* __restrict__ W, unsigned short* __restrict__ wsh) {
  int t = blockIdx.x * 256 + threadIdx.x;      // 102400 total
  int khkw = t >> 12;
  int rem  = t & 4095;
  int ch = rem >> 4, ia = rem & 15;
  wsh[t] = f2h(W[khkw * 4096 + ia * 256 + ch]);
}

// Bank swizzle for votes LDS: XOR byte bits 4-6 with (ch>>3)&7.
#define VSWZ(byteoff, ch) ((byteoff) ^ ((((ch) >> 3) & 7) << 4))

// LDS map (39936 B total):
//   conv phase:  X fp16 [kh 5][ii 8, stride 400B][12 wl][16 ia] = 16000 B @0
//   routing:     votesH fp16 [w 8][ch 256][ii 8] swizzled = 32768 @0 (aliases X)
//                actH   fp16 [w 8][ch 256]   = 4096 @32768
//                logitL f32  [w 8][ii 8][c 8] = 2048 @36864
//                routeH fp16 [w 8][c 8][ii 8] = 1024 @38912
__global__ __launch_bounds__(256, 4) void capsconv_mfma_kernel(
    const float* __restrict__ inp,            // [16][32][32][8][16] f32
    const unsigned short* __restrict__ wsh,   // [25][256][16] fp16
    const float* __restrict__ bias,           // [256] f32
    float* __restrict__ out)                  // [16][32][32][256] f32
{
  __shared__ char smem[39936];
  const _Float16* wshh = (const _Float16*)wsh;
  char* votesB = smem;
  _Float16* actH   = (_Float16*)(smem + 32768);
  float*    logitL = (float*)(smem + 36864);
  _Float16* routeH = (_Float16*)(smem + 38912);

  const int tid  = threadIdx.x;
  const int wid  = tid >> 6;          // wave 0..3 -> ch quarter
  const int lane = tid & 63;
  const int sub  = lane >> 5;
  const int ln31 = lane & 31;

  const int bid = blockIdx.x;         // 2048 = ((bb*32 + h)*4 + wq)
  const int wq = bid & 3;
  const int h  = (bid >> 2) & 31;
  const int bb = bid >> 7;
  const int i_src  = bb >> 1;         // TF reshape scramble (verified r1/r4)
  const int b_base = (bb & 1) * 8;

  // ---------------- stage all 5 X rows (zero-padded halo) ----------------
  for (int e = tid; e < 1920; e += 256) {
    int kh = e / 384; int r1 = e - kh * 384;
    int ii = r1 / 48; int r2 = r1 - ii * 48;
    int wl = r2 >> 2; int iaq = r2 & 3;
    int hh = h + kh - 2;
    int wsrc = wq * 8 + wl - 2;
    float4 v = make_float4(0.f, 0.f, 0.f, 0.f);
    if ((unsigned)hh < 32u && (unsigned)wsrc < 32u)
      v = *(const float4*)(inp +
          ((((size_t)(b_base + ii) * 32 + hh) * 32 + wsrc) * 8 + i_src) * 16 + iaq * 4);
    union { _Float16 hx[4]; unsigned long long u; } pk;
    pk.hx[0] = (_Float16)v.x; pk.hx[1] = (_Float16)v.y;
    pk.hx[2] = (_Float16)v.z; pk.hx[3] = (_Float16)v.w;
    *(unsigned long long*)(smem + kh * 3200 + ii * 400 + wl * 32 + iaq * 8) = pk.u;
  }
  __syncthreads();

  // ---------------- conv: 25 taps, no barriers ----------------
  f32x16 acc[2][2];
  #pragma unroll
  for (int mt = 0; mt < 2; ++mt)
    #pragma unroll
    for (int nt = 0; nt < 2; ++nt)
      #pragma unroll
      for (int e = 0; e < 16; ++e) acc[mt][nt][e] = 0.f;

  #pragma unroll 1
  for (int kh = 0; kh < 5; ++kh) {
    #pragma unroll
    for (int kw = 0; kw < 5; ++kw) {
      f16x8 afrag[2], bfrag[2];
      #pragma unroll
      for (int mt = 0; mt < 2; ++mt) {
        int r = mt * 32 + ln31;                 // block row: w_local = r>>3, ii = r&7
        afrag[mt] = *(const f16x8*)(smem + kh * 3200 + (r & 7) * 400 +
                                    ((r >> 3) + kw) * 32 + sub * 16);
      }
      #pragma unroll
      for (int nt = 0; nt < 2; ++nt) {
        int ch = wid * 64 + nt * 32 + ln31;
        bfrag[nt] = *(const f16x8*)(wshh + (size_t)(kh * 5 + kw) * 4096 + ch * 16 + sub * 8);
      }
      #pragma unroll
      for (int mt = 0; mt < 2; ++mt)
        #pragma unroll
        for (int nt = 0; nt < 2; ++nt)
          acc[mt][nt] = __builtin_amdgcn_mfma_f32_32x32x16_f16(
              afrag[mt], bfrag[nt], acc[mt][nt], 0, 0, 0);
    }
  }

  // ---------------- votes -> LDS fp16 [w][ch][ii], swizzled ----------------
  __syncthreads();   // X region dead after this; votes alias it
  #pragma unroll
  for (int mt = 0; mt < 2; ++mt)
    #pragma unroll
    for (int nt = 0; nt < 2; ++nt) {
      int ch = wid * 64 + nt * 32 + ln31;
      #pragma unroll
      for (int q = 0; q < 4; ++q) {
        // regs 4q..4q+3: row = t + 8q + 4sub -> w = mt*4+q, ii = t + 4sub
        int w = mt * 4 + q;
        union { _Float16 hx[4]; unsigned long long u; } pk;
        #pragma unroll
        for (int t = 0; t < 4; ++t) pk.hx[t] = (_Float16)acc[mt][nt][q * 4 + t];
        int byte = (w * 256 + ch) * 16 + sub * 8;
        *(unsigned long long*)(votesB + VSWZ(byte, ch)) = pk.u;
      }
    }
  __syncthreads();

  // ---------------- routing ----------------
  const int c_own = tid >> 5;
  const float bv = bias[tid];
  const int ag_w = tid >> 5;          // agreement task: (w, c, g)
  const int ag_c = (tid >> 2) & 7;
  const int ag_g = tid & 3;

  // cache this thread's 8 vote fragments (ch = tid) in registers
  f16x8 vreg[8];
  #pragma unroll
  for (int w = 0; w < 8; ++w) {
    int byte = (w * 256 + tid) * 16;
    vreg[w] = *(const f16x8*)(votesB + VSWZ(byte, tid));
  }

  #pragma unroll 1
  for (int rt = 0; rt < 3; ++rt) {
    if (rt > 0) {
      if (tid < 64) {                 // softmax over c per (w, ii)
        int wv = tid >> 3, ii = tid & 7;
        float l[8];
        #pragma unroll
        for (int c = 0; c < 8; ++c) l[c] = logitL[(wv * 8 + ii) * 8 + c];
        float mx = fmaxf(fmaxf(fmaxf(l[0], l[1]), fmaxf(l[2], l[3])),
                         fmaxf(fmaxf(l[4], l[5]), fmaxf(l[6], l[7])));
        float den = 0.f;
        #pragma unroll
        for (int c = 0; c < 8; ++c) den += __expf(l[c] - mx);
        float inv = 1.f / den;
        #pragma unroll
        for (int c = 0; c < 8; ++c)
          routeH[(wv * 8 + c) * 8 + ii] = (_Float16)(__expf(l[c] - mx) * inv);
      }
      __syncthreads();
    }
    // weighted sum + squash; thread owns ch = tid
    #pragma unroll
    for (int w = 0; w < 8; ++w) {
      float pre = bv;
      if (rt == 0) {
        float s = 0.f;
        #pragma unroll
        for (int i = 0; i < 8; ++i) s += (float)vreg[w][i];
        pre = fmaf(0.125f, s, pre);
      } else {
        f16x8 rp = *(const f16x8*)(routeH + (w * 8 + c_own) * 8);
        #pragma unroll
        for (int i = 0; i < 8; ++i) pre = fmaf((float)rp[i], (float)vreg[w][i], pre);
      }
      float nsq = pre * pre;
      #pragma unroll
      for (int m = 16; m >= 1; m >>= 1) nsq += __shfl_xor(nsq, m, 64);
      float av = pre * (sqrtf(nsq) / (1.f + nsq));
      if (rt == 2)
        out[((size_t)((bb * 32 + h) * 32 + wq * 8 + w)) * 256 + tid] = av;
      else
        actH[w * 256 + tid] = (_Float16)av;
    }
    if (rt < 2) {
      __syncthreads();
      // agreement: dot(vote, act) over 32 atoms; (w,c) split over 4 g-lanes
      float dot8[8];
      #pragma unroll
      for (int i = 0; i < 8; ++i) dot8[i] = 0.f;
      #pragma unroll
      for (int j0 = 0; j0 < 8; ++j0) {
        int a = ag_g * 8 + ((j0 + ag_c) & 7);       // c-staggered
        int ch = ag_c * 32 + a;
        int byte = (ag_w * 256 + ch) * 16;
        f16x8 vp = *(const f16x8*)(votesB + VSWZ(byte, ch));
        float av = (float)actH[ag_w * 256 + ch];
        #pragma unroll
        for (int ii = 0; ii < 8; ++ii) dot8[ii] = fmaf((float)vp[ii], av, dot8[ii]);
      }
      #pragma unroll
      for (int ii = 0; ii < 8; ++ii) {
        dot8[ii] += __shfl_xor(dot8[ii], 1, 64);
        dot8[ii] += __shfl_xor(dot8[ii], 2, 64);
      }
      if (ag_g == 0) {
        #pragma unroll
        for (int ii = 0; ii < 8; ++ii) {
          int idx = (ag_w * 8 + ii) * 8 + ag_c;
          if (rt == 0) logitL[idx] = dot8[ii];
          else         logitL[idx] += dot8[ii];
        }
      }
      __syncthreads();
    }
  }
}

extern "C" void kernel_launch(void* const* d_in, const int* in_sizes, int n_in,
                              void* d_out, int out_size, void* d_ws, size_t ws_size,
                              hipStream_t stream) {
  (void)in_sizes; (void)n_in; (void)ws_size; (void)out_size;
  const float* inp  = (const float*)d_in[0];
  const float* W    = (const float*)d_in[1];
  const float* bv   = (const float*)d_in[2];
  float* out        = (float*)d_out;
  unsigned short* wsh = (unsigned short*)d_ws;   // 204800 B used

  hipLaunchKernelGGL(wprep_kernel, dim3(400), dim3(256), 0, stream, W, wsh);
  hipLaunchKernelGGL(capsconv_mfma_kernel, dim3(2048), dim3(256), 0, stream,
                     inp, wsh, bv, out);
}